// Round 5
// baseline (22.006 us; speedup 1.0000x reference)
//
#include <hip/hip_runtime.h>

// CompositeLoss: boundary-weighted BCE + Dice over (32,1,512,512)
// pred: float32 uniform [0,1), target: int32 binary {0,1}
// out: [total, bce, dice] float32
//
// R4 = R3 (passed, absmax 0.0) + ONE structural change: each wave handles a
// 2-row vertical strip (center rows h0, h0+1), loading 4 target rows instead
// of 6 for the same coverage (vertical redundancy 3x -> 1.5x, VMEM instrs
// 16 -> 12 per 16 px), single pass (no grid-stride loop), all loads up front.
// Horizontal window + shuffle-halo logic is verbatim R3, applied per row.
// Partials are float4; finalize uses 1024 threads with vector loads.

#define BB 32
#define HH 512
#define WW 512
#define N_TOTAL (BB * HH * WW)
#define NBLK 2048                 // 4 waves/block, 1 wave = one 2-row strip

__global__ __launch_bounds__(256) void loss_main_kernel(
        const float* __restrict__ pred,
        const int* __restrict__ target,
        float4* __restrict__ partials) {
    const int wave = threadIdx.x >> 6;
    const int lane = threadIdx.x & 63;
    const int gw   = blockIdx.x * 4 + wave;   // strip id, 0..8191
    const int b    = gw >> 8;                 // 256 strips per image
    const int h0   = (gw & 255) << 1;         // center rows h0, h0+1
    const int w0   = lane << 3;               // 8 contiguous px per lane

    const size_t img = (size_t)b * (HH * WW);
    const int* tg   = target + img;
    const float* pg = pred + img;

    const int hm = (h0 > 0) ? h0 - 1 : 0;            // clamp top
    const int hp = (h0 + 2 < HH) ? h0 + 2 : HH - 1;  // clamp bottom

    // ---- 4 target rows x 8 cols, 2 pred rows x 8 cols (all coalesced) ----
    const int4 r0A = *(const int4*)(tg + (size_t)hm * WW + w0);
    const int4 r0B = *(const int4*)(tg + (size_t)hm * WW + w0 + 4);
    const int4 r1A = *(const int4*)(tg + (size_t)h0 * WW + w0);
    const int4 r1B = *(const int4*)(tg + (size_t)h0 * WW + w0 + 4);
    const int4 r2A = *(const int4*)(tg + (size_t)(h0 + 1) * WW + w0);
    const int4 r2B = *(const int4*)(tg + (size_t)(h0 + 1) * WW + w0 + 4);
    const int4 r3A = *(const int4*)(tg + (size_t)hp * WW + w0);
    const int4 r3B = *(const int4*)(tg + (size_t)hp * WW + w0 + 4);

    const float4 pT0 = *(const float4*)(pg + (size_t)h0 * WW + w0);
    const float4 pT1 = *(const float4*)(pg + (size_t)h0 * WW + w0 + 4);
    const float4 pB0 = *(const float4*)(pg + (size_t)(h0 + 1) * WW + w0);
    const float4 pB1 = *(const float4*)(pg + (size_t)(h0 + 1) * WW + w0 + 4);

    // ---- vertical or/and per column, both center rows (share middle pair) --
#define VC(i, u, c1, c2, d)                                          \
    const int so##i = (c1) | (c2), sa##i = (c1) & (c2);              \
    const int oT##i = so##i | (u), nT##i = sa##i & (u);              \
    const int oB##i = so##i | (d), nB##i = sa##i & (d);
    VC(0, r0A.x, r1A.x, r2A.x, r3A.x)
    VC(1, r0A.y, r1A.y, r2A.y, r3A.y)
    VC(2, r0A.z, r1A.z, r2A.z, r3A.z)
    VC(3, r0A.w, r1A.w, r2A.w, r3A.w)
    VC(4, r0B.x, r1B.x, r2B.x, r3B.x)
    VC(5, r0B.y, r1B.y, r2B.y, r3B.y)
    VC(6, r0B.z, r1B.z, r2B.z, r3B.z)
    VC(7, r0B.w, r1B.w, r2B.w, r3B.w)
#undef VC

    // ---- halo columns via shuffle (wave spans the whole row), per row ----
    int oTL = __shfl_up(oT7, 1),   nTL = __shfl_up(nT7, 1);
    int oTR = __shfl_down(oT0, 1), nTR = __shfl_down(nT0, 1);
    int oBL = __shfl_up(oB7, 1),   nBL = __shfl_up(nB7, 1);
    int oBR = __shfl_down(oB0, 1), nBR = __shfl_down(nB0, 1);
    if (lane == 0)  { oTL = oT0; nTL = nT0; oBL = oB0; nBL = nB0; }
    if (lane == 63) { oTR = oT7; nTR = nT7; oBR = oB7; nBR = nB7; }

    // ---- horizontal window -> boundary flags (verbatim R3, per row) ----
    const int eT0 = (oTL | oT0 | oT1) != (nTL & nT0 & nT1);
    const int eT1 = (oT0 | oT1 | oT2) != (nT0 & nT1 & nT2);
    const int eT2 = (oT1 | oT2 | oT3) != (nT1 & nT2 & nT3);
    const int eT3 = (oT2 | oT3 | oT4) != (nT2 & nT3 & nT4);
    const int eT4 = (oT3 | oT4 | oT5) != (nT3 & nT4 & nT5);
    const int eT5 = (oT4 | oT5 | oT6) != (nT4 & nT5 & nT6);
    const int eT6 = (oT5 | oT6 | oT7) != (nT5 & nT6 & nT7);
    const int eT7 = (oT6 | oT7 | oTR) != (nT6 & nT7 & nTR);
    const int eB0 = (oBL | oB0 | oB1) != (nBL & nB0 & nB1);
    const int eB1 = (oB0 | oB1 | oB2) != (nB0 & nB1 & nB2);
    const int eB2 = (oB1 | oB2 | oB3) != (nB1 & nB2 & nB3);
    const int eB3 = (oB2 | oB3 | oB4) != (nB2 & nB3 & nB4);
    const int eB4 = (oB3 | oB4 | oB5) != (nB3 & nB4 & nB5);
    const int eB5 = (oB4 | oB5 | oB6) != (nB4 & nB5 & nB6);
    const int eB6 = (oB5 | oB6 | oB7) != (nB5 & nB6 & nB7);
    const int eB7 = (oB6 | oB7 | oBR) != (nB6 & nB7 & nBR);

    float wbce = 0.f, inter = 0.f, sp = 0.f;
    int st_i = 0;

#define ACC(T, P, E)                                                   \
    {                                                                  \
        const float pc = fminf(fmaxf((P), 1e-7f), 1.0f - 1e-7f);       \
        const float x  = (T) ? pc : (1.0f - pc);                       \
        wbce += ((E) ? 3.0f : 1.0f) * (-__logf(x));                    \
        sp += (P);                                                     \
        if (T) inter += (P);                                           \
        st_i += (T);                                                   \
    }
    ACC(r1A.x, pT0.x, eT0); ACC(r1A.y, pT0.y, eT1);
    ACC(r1A.z, pT0.z, eT2); ACC(r1A.w, pT0.w, eT3);
    ACC(r1B.x, pT1.x, eT4); ACC(r1B.y, pT1.y, eT5);
    ACC(r1B.z, pT1.z, eT6); ACC(r1B.w, pT1.w, eT7);
    ACC(r2A.x, pB0.x, eB0); ACC(r2A.y, pB0.y, eB1);
    ACC(r2A.z, pB0.z, eB2); ACC(r2A.w, pB0.w, eB3);
    ACC(r2B.x, pB1.x, eB4); ACC(r2B.y, pB1.y, eB5);
    ACC(r2B.z, pB1.z, eB6); ACC(r2B.w, pB1.w, eB7);
#undef ACC

    // ---- wave reduction, then one float4 partial per block ----
    float st = (float)st_i;
    #pragma unroll
    for (int off = 32; off > 0; off >>= 1) {
        wbce  += __shfl_down(wbce,  off);
        inter += __shfl_down(inter, off);
        sp    += __shfl_down(sp,    off);
        st    += __shfl_down(st,    off);
    }

    __shared__ float smem[4][4];
    if ((threadIdx.x & 63) == 0) {
        smem[wave][0] = wbce; smem[wave][1] = inter;
        smem[wave][2] = sp;   smem[wave][3] = st;
    }
    __syncthreads();
    if (threadIdx.x == 0) {
        float s0 = 0, s1 = 0, s2 = 0, s3 = 0;
        #pragma unroll
        for (int wv = 0; wv < 4; ++wv) {
            s0 += smem[wv][0]; s1 += smem[wv][1];
            s2 += smem[wv][2]; s3 += smem[wv][3];
        }
        partials[blockIdx.x] = make_float4(s0, s1, s2, s3);
    }
}

__global__ __launch_bounds__(1024) void finalize_kernel(
        const float4* __restrict__ partials, float* __restrict__ out) {
    double a0 = 0, a1 = 0, a2 = 0, a3 = 0;
    #pragma unroll
    for (int k = 0; k < NBLK / 1024; ++k) {
        const float4 p = partials[k * 1024 + threadIdx.x];
        a0 += p.x; a1 += p.y; a2 += p.z; a3 += p.w;
    }
    #pragma unroll
    for (int off = 32; off > 0; off >>= 1) {
        a0 += __shfl_down(a0, off);
        a1 += __shfl_down(a1, off);
        a2 += __shfl_down(a2, off);
        a3 += __shfl_down(a3, off);
    }
    __shared__ double smem[16][4];
    const int wave = threadIdx.x >> 6;
    if ((threadIdx.x & 63) == 0) {
        smem[wave][0] = a0; smem[wave][1] = a1;
        smem[wave][2] = a2; smem[wave][3] = a3;
    }
    __syncthreads();
    if (threadIdx.x == 0) {
        double s0 = 0, s1 = 0, s2 = 0, s3 = 0;
        #pragma unroll
        for (int wv = 0; wv < 16; ++wv) {
            s0 += smem[wv][0]; s1 += smem[wv][1];
            s2 += smem[wv][2]; s3 += smem[wv][3];
        }
        const double bce = s0 / (double)N_TOTAL;
        const double dice_coef = (2.0 * s1 + 1e-6) / (s2 + s3 + 1e-6);
        const double dice = 1.0 - dice_coef;
        const double total = 0.5 * bce + 0.5 * dice;
        out[0] = (float)total;
        out[1] = (float)bce;
        out[2] = (float)dice;
    }
}

extern "C" void kernel_launch(void* const* d_in, const int* in_sizes, int n_in,
                              void* d_out, int out_size, void* d_ws, size_t ws_size,
                              hipStream_t stream) {
    const float* pred  = (const float*)d_in[0];
    const int* target  = (const int*)d_in[1];
    float* out = (float*)d_out;
    float4* partials = (float4*)d_ws;   // NBLK float4 = 32 KB

    loss_main_kernel<<<NBLK, 256, 0, stream>>>(pred, target, partials);
    finalize_kernel<<<1, 1024, 0, stream>>>(partials, out);
}